// Round 5
// baseline (205.364 us; speedup 1.0000x reference)
//
#include <hip/hip_runtime.h>
#include <hip/hip_bf16.h>
#include <stdint.h>

#define NNODE 65536
#define NEDGE 65536
#define ETOT  (NNODE + NEDGE)
#define INC   512
#define OUTC  256
#define NEG_SLOPE 0.2f
#define SLOTCAP 32

typedef __attribute__((ext_vector_type(8))) __bf16 bf16x8;
typedef __attribute__((ext_vector_type(4))) float f32x4;

__device__ __forceinline__ float b2f(unsigned short u) {
  return __uint_as_float(((unsigned int)u) << 16);
}
__device__ __forceinline__ unsigned short f2b(float f) {
  unsigned int u = __float_as_uint(f);
  u += 0x7fffu + ((u >> 16) & 1u);
  return (unsigned short)(u >> 16);
}
__device__ __forceinline__ unsigned int pk2(float lo, float hi) {
  return (unsigned int)f2b(lo) | ((unsigned int)f2b(hi) << 16);
}
__device__ __forceinline__ float lrelu(float v) {
  return v > 0.f ? v : NEG_SLOPE * v;
}

// ---------------- prep: f32 -> bf16 of x ----------------
__global__ __launch_bounds__(256) void cvt_x_kernel(const float* __restrict__ x,
                                                    unsigned short* __restrict__ xb) {
  size_t i = ((size_t)blockIdx.x * 256 + threadIdx.x) * 4;
  float4 v = *(const float4*)(x + i);
  ushort4 o = { f2b(v.x), f2b(v.y), f2b(v.z), f2b(v.w) };
  *(ushort4*)(xb + i) = o;
}

// ---------------- prep: W concat transposed (768x512 bf16) + bias concat ----------------
__global__ __launch_bounds__(256) void prep_w_kernel(
    const float* __restrict__ Wl, const float* __restrict__ Wr, const float* __restrict__ Ws,
    const float* __restrict__ bl, const float* __restrict__ br, const float* __restrict__ bs,
    unsigned short* __restrict__ WT, float* __restrict__ bcat) {
  int i = blockIdx.x * 256 + threadIdx.x;
  if (i < 768 * 512) {
    int o = i >> 9, k = i & 511;
    float v;
    if (o < 256)      v = Wl[k * 256 + o];
    else if (o < 512) v = Wr[k * 256 + (o - 256)];
    else              v = Ws[k * 256 + (o - 512)];
    WT[i] = f2b(v);
  }
  if (i < 768) {
    bcat[i] = (i < 256) ? bl[i] : (i < 512 ? br[i - 256] : bs[i - 512]);
  }
}

// ---------------- fused GEMM: [N,512]bf16 @ [512,768]bf16 -> xl, xr, x_self (all bf16) ----------------
// 256x256 tile, BK=64, 8 waves (2Mx4N, per-wave 128x64), 128KB LDS double-buffer,
// burst stage (8 x global_load_lds/thread) + counted vmcnt(8) with one-K-tile lead (T3/T4),
// 2 barriers per K-tile, setprio around MFMA (T5), XCD swizzle (T1), XOR slot swizzle (T2 rule 21).
__global__ __launch_bounds__(512) void gemm_kernel(
    const unsigned short* __restrict__ Xb,   // [65536][512]
    const unsigned short* __restrict__ WT,   // [768][512]
    const float* __restrict__ bcat,          // [768]
    unsigned short* __restrict__ xl,         // [65536][256] bf16
    unsigned short* __restrict__ xr,         // [65536][256] bf16
    unsigned short* __restrict__ xs) {       // [65536][256] bf16 (x_self)
  __shared__ __align__(16) char smem[131072];     // 2 x (A 32KB + B 32KB); epilogue reuses 34.8KB
  unsigned short* sm = (unsigned short*)smem;     // buf b: A at b*32768 shorts... (bytes b*65536)

  // XCD swizzle: 768 blocks = 8 XCDs x 96; 3 col-tiles sharing an A row-panel stay on one XCD.
  const int wid = blockIdx.x;
  const int xcd = wid & 7;
  const int local = wid >> 3;              // 0..95
  const int by = local % 3;                // col tile 0..2  (0->xl, 1->xr, 2->xs)
  const int rowt = xcd * 32 + local / 3;   // row tile 0..255
  const int rowBase = rowt * 256;
  const int colBase = by * 256;

  const int tid = threadIdx.x;
  const int lane = tid & 63;
  const int w = tid >> 6;        // wave 0..7
  const int wm = (w >> 2) * 128; // wave row offset within tile
  const int wn = (w & 3) * 64;   // wave col offset within tile

  f32x4 acc[8][4] = {};

  // stage one full K-tile (A 256x64 + B 256x64 bf16 = 64KB) : 8 global_load_lds of 16B per thread.
  // LDS linear dest; source slot pre-XOR-swizzled (rule 21). Row = 128B = 8 slots of 16B.
  auto stage = [&](int kk, int buf) {
    const int q = tid;                 // 0..511
    const int slot_sw = q & 7;
#pragma unroll
    for (int l = 0; l < 4; ++l) {
      const int r = l * 64 + (q >> 3);           // tile row 0..255
      const int slot = slot_sw ^ (r & 7);
      const unsigned short* gA = Xb + (size_t)(rowBase + r) * 512 + kk + slot * 8;
      __builtin_amdgcn_global_load_lds(
          (const __attribute__((address_space(1))) void*)gA,
          (__attribute__((address_space(3))) void*)(sm + buf * 32768 + l * 4096 + q * 8), 16, 0, 0);
      const unsigned short* gB = WT + (size_t)(colBase + r) * 512 + kk + slot * 8;
      __builtin_amdgcn_global_load_lds(
          (const __attribute__((address_space(1))) void*)gB,
          (__attribute__((address_space(3))) void*)(sm + buf * 32768 + 16384 + l * 4096 + q * 8), 16, 0, 0);
    }
  };

#define COMPUTE(bufidx) { \
    const unsigned short* As = sm + (bufidx) * 32768; \
    const unsigned short* Bs = As + 16384; \
    _Pragma("unroll") \
    for (int kh = 0; kh < 2; ++kh) { \
      bf16x8 bfr[4]; \
      _Pragma("unroll") \
      for (int n = 0; n < 4; ++n) { \
        const int rB = wn + n * 16 + (lane & 15); \
        const int sB = (kh * 4 + (lane >> 4)) ^ (rB & 7); \
        bfr[n] = *(const bf16x8*)&Bs[rB * 64 + sB * 8]; \
      } \
      _Pragma("unroll") \
      for (int m = 0; m < 8; ++m) { \
        const int rA = wm + m * 16 + (lane & 15); \
        const int sA = (kh * 4 + (lane >> 4)) ^ (rA & 7); \
        bf16x8 afr = *(const bf16x8*)&As[rA * 64 + sA * 8]; \
        __builtin_amdgcn_s_setprio(1); \
        _Pragma("unroll") \
        for (int n = 0; n < 4; ++n) \
          acc[m][n] = __builtin_amdgcn_mfma_f32_16x16x32_bf16(afr, bfr[n], acc[m][n], 0, 0, 0); \
        __builtin_amdgcn_s_setprio(0); \
      } \
    } \
  }

  // prologue: two K-tiles in flight
  stage(0, 0);
  stage(64, 1);
  asm volatile("s_waitcnt vmcnt(8)" ::: "memory");   // T0 landed (T1 still flying)
  __builtin_amdgcn_s_barrier();

  for (int t = 0; t < 8; ++t) {
    const int buf = t & 1;
    __builtin_amdgcn_sched_barrier(0);
    COMPUTE(buf);
    __builtin_amdgcn_sched_barrier(0);
    __builtin_amdgcn_s_barrier();                    // all waves done reading buf -> free
    if (t + 2 < 8) {
      stage((t + 2) * 64, buf);                      // refill freed buf with T(t+2)
      asm volatile("s_waitcnt vmcnt(8)" ::: "memory");  // T(t+1) landed; T(t+2) flying
    } else {
      asm volatile("s_waitcnt vmcnt(0)" ::: "memory");  // drain tail (t=6 waits T7)
    }
    __builtin_amdgcn_s_barrier();                    // all threads' next-buf data landed
  }
#undef COMPUTE

  // epilogue: all three outputs bf16; restage per-wave through LDS for 128B-contiguous stores.
  // D frag layout: col = lane&15, row = (lane>>4)*4 + j   [m89-verified]
  {
    unsigned short* dst = (by == 0) ? xl : (by == 1) ? xr : xs;
    float* eps = (float*)smem + w * 1088;   // per-wave 16x68 f32 (4352B x 8 waves)
    float biasn[4];
#pragma unroll
    for (int n = 0; n < 4; ++n) biasn[n] = bcat[colBase + wn + n * 16 + (lane & 15)];
#pragma unroll
    for (int m = 0; m < 8; ++m) {
#pragma unroll
      for (int n = 0; n < 4; ++n)
#pragma unroll
        for (int j = 0; j < 4; ++j)
          eps[((lane >> 4) * 4 + j) * 68 + n * 16 + (lane & 15)] = acc[m][n][j] + biasn[n];
#pragma unroll
      for (int it = 0; it < 2; ++it) {
        const int r16 = it * 8 + (lane >> 3);
        const int c8 = (lane & 7) * 8;
        const float* srcp = eps + r16 * 68 + c8;
        float4 v0 = *(const float4*)srcp;
        float4 v1 = *(const float4*)(srcp + 4);
        uint4 o;
        o.x = pk2(v0.x, v0.y);
        o.y = pk2(v0.z, v0.w);
        o.z = pk2(v1.x, v1.y);
        o.w = pk2(v1.z, v1.w);
        *(uint4*)(dst + (size_t)(rowBase + wm + m * 16 + r16) * 256 + wn + c8) = o;
      }
    }
  }
}

// ---------------- per-edge attention logits (half-wave per edge) + direct slot scatter ----------------
__global__ __launch_bounds__(256) void edge_logit_kernel(
    const int* __restrict__ ei,          // [2][NEDGE]
    const unsigned short* __restrict__ xl,
    const unsigned short* __restrict__ xr,
    const float* __restrict__ att,
    int* __restrict__ cnt,
    int* __restrict__ slot_src,          // [NNODE][SLOTCAP]
    float* __restrict__ slot_e) {        // [NNODE][SLOTCAP]
  const int j = blockIdx.x * 8 + (threadIdx.x >> 5);
  const int lane = threadIdx.x & 31;
  int src, dst;
  if (j < NEDGE) { src = ei[j]; dst = ei[NEDGE + j]; }
  else           { src = j - NEDGE; dst = src; }
  const int c = lane * 8;
  uint4 ul = *(const uint4*)(xl + (size_t)src * 256 + c);
  uint4 ur = *(const uint4*)(xr + (size_t)dst * 256 + c);
  float4 a0 = *(const float4*)(att + c);
  float4 a1 = *(const float4*)(att + c + 4);
  float s = lrelu(b2f((unsigned short)ul.x) + b2f((unsigned short)ur.x)) * a0.x
          + lrelu(b2f((unsigned short)(ul.x >> 16)) + b2f((unsigned short)(ur.x >> 16))) * a0.y
          + lrelu(b2f((unsigned short)ul.y) + b2f((unsigned short)ur.y)) * a0.z
          + lrelu(b2f((unsigned short)(ul.y >> 16)) + b2f((unsigned short)(ur.y >> 16))) * a0.w
          + lrelu(b2f((unsigned short)ul.z) + b2f((unsigned short)ur.z)) * a1.x
          + lrelu(b2f((unsigned short)(ul.z >> 16)) + b2f((unsigned short)(ur.z >> 16))) * a1.y
          + lrelu(b2f((unsigned short)ul.w) + b2f((unsigned short)ur.w)) * a1.z
          + lrelu(b2f((unsigned short)(ul.w >> 16)) + b2f((unsigned short)(ur.w >> 16))) * a1.w;
#pragma unroll
  for (int off = 16; off; off >>= 1) s += __shfl_xor(s, off);
  if (lane == 0) {
    const int pos = atomicAdd(&cnt[dst], 1);
    if (pos < SLOTCAP) {
      slot_src[dst * SLOTCAP + pos] = src;
      slot_e[dst * SLOTCAP + pos] = s;
    }
  }
}

// ---------------- per-node softmax + aggregate + cls logit (wave per node) ----------------
__global__ __launch_bounds__(256) void node_kernel(
    const int* __restrict__ cnt,
    const int* __restrict__ slot_src, const float* __restrict__ slot_e,
    const unsigned short* __restrict__ xl,
    const unsigned short* __restrict__ xs,
    const float* __restrict__ conv_bias,
    float* __restrict__ out,
    const float* __restrict__ Wcls, const float* __restrict__ bcls,
    float* __restrict__ logits) {
  const int n = blockIdx.x * 4 + (threadIdx.x >> 6);
  const int lane = threadIdx.x & 63;
  const int base = n * SLOTCAP;
  const int deg = cnt[n];

  float m = -1e30f;
  for (int k = 0; k < deg; ++k) m = fmaxf(m, slot_e[base + k]);
  float denom = 0.f;
  for (int k = 0; k < deg; ++k) denom += __expf(slot_e[base + k] - m);
  const float inv = 1.f / denom;

  const int c = lane * 4;
  float4 accv = {0.f, 0.f, 0.f, 0.f};
  for (int k = 0; k < deg; ++k) {
    const float alpha = __expf(slot_e[base + k] - m) * inv;
    const int src = slot_src[base + k];
    ushort4 u = *(const ushort4*)(xl + (size_t)src * 256 + c);
    accv.x += alpha * b2f(u.x);
    accv.y += alpha * b2f(u.y);
    accv.z += alpha * b2f(u.z);
    accv.w += alpha * b2f(u.w);
  }
  ushort4 s4 = *(const ushort4*)(xs + (size_t)n * 256 + c);
  float4 cb = *(const float4*)(conv_bias + c);
  float4 cur;
  cur.x = b2f(s4.x) + accv.x + cb.x;
  cur.y = b2f(s4.y) + accv.y + cb.y;
  cur.z = b2f(s4.z) + accv.z + cb.z;
  cur.w = b2f(s4.w) + accv.w + cb.w;
  const size_t o = (size_t)n * 256 + c;
  *(float4*)(out + o) = cur;

  float4 wc = *(const float4*)(Wcls + c);
  float part = cur.x * wc.x + cur.y * wc.y + cur.z * wc.z + cur.w * wc.w;
#pragma unroll
  for (int off = 32; off; off >>= 1) part += __shfl_xor(part, off, 64);
  if (lane == 0) logits[n] = part + bcls[0];
}

// ---------------- sinkhorn row softmax + broadcast add (4 blocks per row) ----------------
__global__ __launch_bounds__(256) void sk_kernel(const float* __restrict__ logits,
                                                 float* __restrict__ out) {
  __shared__ float sv[256];
  __shared__ float red[256];
  const int r = blockIdx.x >> 2;
  const int q = blockIdx.x & 3;
  const int t = threadIdx.x;
  const float v = logits[r * 256 + t];
  red[t] = v;
  __syncthreads();
  for (int d = 128; d; d >>= 1) {
    if (t < d) red[t] = fmaxf(red[t], red[t + d]);
    __syncthreads();
  }
  const float mx = red[0];
  __syncthreads();
  const float p = __expf(v - mx);
  red[t] = p;
  __syncthreads();
  for (int d = 128; d; d >>= 1) {
    if (t < d) red[t] += red[t + d];
    __syncthreads();
  }
  const float sum = red[0];
  sv[t] = p / sum;
  __syncthreads();
  const size_t rowbase = (size_t)r * 256 * 256;
  for (int i = q * 64; i < q * 64 + 64; ++i) {
    out[rowbase + (size_t)i * 256 + t] += sv[i];
  }
}

// ---------------- launch ----------------
extern "C" void kernel_launch(void* const* d_in, const int* in_sizes, int n_in,
                              void* d_out, int out_size, void* d_ws, size_t ws_size,
                              hipStream_t stream) {
  const float* x        = (const float*)d_in[0];
  const int*   ei       = (const int*)d_in[2];
  const float* W_self   = (const float*)d_in[5];
  const float* b_self   = (const float*)d_in[6];
  const float* W_l      = (const float*)d_in[7];
  const float* b_l      = (const float*)d_in[8];
  const float* W_r      = (const float*)d_in[9];
  const float* b_r      = (const float*)d_in[10];
  const float* att      = (const float*)d_in[11];
  const float* conv_bias= (const float*)d_in[12];
  const float* W_cls    = (const float*)d_in[13];
  const float* b_cls    = (const float*)d_in[14];
  float* out = (float*)d_out;

  char* ws = (char*)d_ws;
  size_t off = 0;
  auto alloc = [&](size_t bytes) {
    char* p = ws + off;
    off += (bytes + 255) & ~(size_t)255;
    return p;
  };
  unsigned short* xb   = (unsigned short*)alloc((size_t)NNODE * INC * 2);  // dead after gemm
  unsigned short* WT   = (unsigned short*)alloc((size_t)768 * 512 * 2);
  float*          bcat = (float*)alloc(768 * 4);
  unsigned short* xlb  = (unsigned short*)alloc((size_t)NNODE * OUTC * 2);
  unsigned short* xrb  = (unsigned short*)alloc((size_t)NNODE * OUTC * 2);
  unsigned short* xsb  = (unsigned short*)alloc((size_t)NNODE * OUTC * 2);
  int*            cnt  = (int*)alloc((size_t)NNODE * 4);
  float*          logits  = (float*)alloc((size_t)NNODE * 4);
  // slot arrays overlay xb (dead after gemm): 65536*32*(4+4) = 16.8 MB << 64 MB
  int*   slot_src = (int*)xb;
  float* slot_e   = (float*)(xb + (size_t)NNODE * SLOTCAP * 2);
  (void)ws_size; (void)in_sizes; (void)n_in; (void)out_size;

  hipMemsetAsync(cnt, 0, (size_t)NNODE * 4, stream);

  cvt_x_kernel<<<(NNODE * INC) / (256 * 4), 256, 0, stream>>>(x, xb);
  prep_w_kernel<<<(768 * 512 + 255) / 256, 256, 0, stream>>>(W_l, W_r, W_self, b_l, b_r, b_self, WT, bcat);
  gemm_kernel<<<768, 512, 0, stream>>>(xb, WT, bcat, xlb, xrb, xsb);
  edge_logit_kernel<<<ETOT / 8, 256, 0, stream>>>(ei, xlb, xrb, att, cnt, slot_src, slot_e);
  node_kernel<<<NNODE / 4, 256, 0, stream>>>(cnt, slot_src, slot_e, xlb, xsb, conv_bias,
                                             out, W_cls, b_cls, logits);
  sk_kernel<<<1024, 256, 0, stream>>>(logits, out);
}